// Round 1
// baseline (238.172 us; speedup 1.0000x reference)
//
#include <hip/hip_runtime.h>
#include <stdint.h>

#define T 4096
#define E 64
#define NWIN 32
#define NBH 32
#define KK_LD 136            // 128 + 8 pad (bf16 elems)
#define VT_LD 264            // 256 + 8 pad
#define PB_STRIDE (16*264)   // per-wave P buffer elems
#define KK_BYTES 69632       // 256*136*2
#define SMEM_BYTES 103424    // KK/Pbuf overlay (69632) + Vt (33792)

typedef __attribute__((ext_vector_type(8))) short short8;
typedef __attribute__((ext_vector_type(4))) short short4v;
typedef __attribute__((ext_vector_type(4))) float f32x4;

__device__ __forceinline__ short f2bf(float x) {
  unsigned u = __float_as_uint(x);
  u += 0x7fffu + ((u >> 16) & 1u);   // round-to-nearest-even
  return (short)(u >> 16);
}

// One block per (window, bh). 8 waves, each owns 16 q-rows.
__global__ __launch_bounds__(512, 2)
void la_kernel(const float* __restrict__ qg, const float* __restrict__ kg,
               const float* __restrict__ qrg, const float* __restrict__ krg,
               const float* __restrict__ vg, float* __restrict__ outg) {
  extern __shared__ char smem[];
  short* KK = (short*)smem;                 // phase 1: [256][136] = [K|Kr] bf16
  short* Pb = (short*)smem;                 // phase 2: [8 waves][16][264] bf16
  short* Vt = (short*)(smem + KK_BYTES);    // [64][264] bf16 (V transposed)

  const int w   = blockIdx.x;
  const int bh  = blockIdx.y;
  const int tid = threadIdx.x;
  const int wid  = tid >> 6;    // wave 0..7
  const int lane = tid & 63;
  const int li = lane & 15;
  const int lg = lane >> 4;

  const size_t base = (size_t)bh * T * E;
  const int krow0 = w * 128 - 128;   // global t-row of key-tile row 0

  // ---- Q/Qr -> A-fragments in registers (scale folded; exact pow2) ----
  // A-layout: lane holds A[m=li][k = kt*32 + lg*8 + j], k-dim = [Q e 0..63 | Qr e 0..63]
  const int qrow = w * 128 + wid * 16 + li;
  const float* qp  = qg  + base + (size_t)qrow * E;
  const float* qrp = qrg + base + (size_t)qrow * E;
  short8 aF[4];
#pragma unroll
  for (int kt = 0; kt < 4; ++kt) {
    const float* sp = (kt < 2 ? qp : qrp) + (kt & 1) * 32 + lg * 8;
    float4 f0 = *(const float4*)sp;
    float4 f1 = *(const float4*)(sp + 4);
    short8 a;
    a[0]=f2bf(f0.x*0.125f); a[1]=f2bf(f0.y*0.125f); a[2]=f2bf(f0.z*0.125f); a[3]=f2bf(f0.w*0.125f);
    a[4]=f2bf(f1.x*0.125f); a[5]=f2bf(f1.y*0.125f); a[6]=f2bf(f1.z*0.125f); a[7]=f2bf(f1.w*0.125f);
    aF[kt] = a;
  }

  // ---- stage K,Kr -> KK[row][0:64 | 64:128], zero-fill pad window (w==0) ----
#pragma unroll
  for (int m = 0; m < 2; ++m) {
    const float* src = m ? krg : kg;
#pragma unroll
    for (int it = 0; it < 8; ++it) {
      int idx = it * 512 + tid;
      int row = idx >> 4, c4 = idx & 15;
      int grow = krow0 + row;
      float4 f = make_float4(0.f, 0.f, 0.f, 0.f);
      if (grow >= 0) f = *(const float4*)(src + base + (size_t)grow * E + c4 * 4);
      short4v h = { f2bf(f.x), f2bf(f.y), f2bf(f.z), f2bf(f.w) };
      *(short4v*)(KK + row * KK_LD + m * 64 + c4 * 4) = h;
    }
  }
  // ---- stage V transposed -> Vt[e][keypos] ----
#pragma unroll
  for (int it = 0; it < 8; ++it) {
    int idx = it * 512 + tid;
    int row = idx >> 4, c4 = idx & 15;
    int grow = krow0 + row;
    float4 f = make_float4(0.f, 0.f, 0.f, 0.f);
    if (grow >= 0) f = *(const float4*)(vg + base + (size_t)grow * E + c4 * 4);
    Vt[(c4*4+0)*VT_LD + row] = f2bf(f.x);
    Vt[(c4*4+1)*VT_LD + row] = f2bf(f.y);
    Vt[(c4*4+2)*VT_LD + row] = f2bf(f.z);
    Vt[(c4*4+3)*VT_LD + row] = f2bf(f.w);
  }
  __syncthreads();

  // ---- S = [Q|Qr]·[K|Kr]^T : 16 col-tiles x 4 k-tiles of 16x16x32 MFMA ----
  // C-layout: lane holds S[row = lg*4 + reg][col = ct*16 + li]
  f32x4 S[16];
#pragma unroll
  for (int ct = 0; ct < 16; ++ct) {
    f32x4 acc = {0.f, 0.f, 0.f, 0.f};
    const short* kb = KK + (ct * 16 + li) * KK_LD + lg * 8;
#pragma unroll
    for (int kt = 0; kt < 4; ++kt) {
      short8 b = *(const short8*)(kb + kt * 32);
      acc = __builtin_amdgcn_mfma_f32_16x16x32_bf16(aF[kt], b, acc, 0, 0, 0);
    }
    S[ct] = acc;
  }

  // ---- mask + softmax (registers + 16-lane shfl reductions) ----
  const int rowb = wid * 16 + lg * 4;
  float linv[4];
#pragma unroll
  for (int r = 0; r < 4; ++r) {
    const int qi = rowb + r;   // 0..127 within window
    float mx = -1e30f;
#pragma unroll
    for (int ct = 0; ct < 16; ++ct) {
      int jj = ct * 16 + li;   // key col 0..255
      bool valid = (jj <= qi + 128) && (w > 0 || jj >= 128);
      float sv = valid ? S[ct][r] : -1e30f;
      S[ct][r] = sv;
      mx = fmaxf(mx, sv);
    }
    mx = fmaxf(mx, __shfl_xor(mx, 1));
    mx = fmaxf(mx, __shfl_xor(mx, 2));
    mx = fmaxf(mx, __shfl_xor(mx, 4));
    mx = fmaxf(mx, __shfl_xor(mx, 8));
    float sm = 0.f;
#pragma unroll
    for (int ct = 0; ct < 16; ++ct) {
      float e = __expf(S[ct][r] - mx);
      S[ct][r] = e;
      sm += e;
    }
    sm += __shfl_xor(sm, 1);
    sm += __shfl_xor(sm, 2);
    sm += __shfl_xor(sm, 4);
    sm += __shfl_xor(sm, 8);
    linv[r] = 1.f / sm;
  }
  __syncthreads();   // all waves done reading KK before Pbuf overlays it

  // ---- P (C-layout regs) -> LDS in row-major, re-read in A-layout ----
  short* pw = Pb + wid * PB_STRIDE;
#pragma unroll
  for (int ct = 0; ct < 16; ++ct) {
#pragma unroll
    for (int r = 0; r < 4; ++r) {
      pw[(lg * 4 + r) * 264 + ct * 16 + li] = f2bf(S[ct][r]);
    }
  }
  __syncthreads();

  // ---- O = P·V : 4 n-tiles x 8 k-tiles ----
  short8 aP[8];
  const short* pr = Pb + wid * PB_STRIDE + li * 264 + lg * 8;
#pragma unroll
  for (int kt = 0; kt < 8; ++kt) aP[kt] = *(const short8*)(pr + kt * 32);
  f32x4 O[4] = {{0,0,0,0},{0,0,0,0},{0,0,0,0},{0,0,0,0}};
#pragma unroll
  for (int kt = 0; kt < 8; ++kt) {
#pragma unroll
    for (int nt = 0; nt < 4; ++nt) {
      short8 b = *(const short8*)(Vt + (nt * 16 + li) * VT_LD + kt * 32 + lg * 8);
      O[nt] = __builtin_amdgcn_mfma_f32_16x16x32_bf16(aP[kt], b, O[nt], 0, 0, 0);
    }
  }

  // ---- epilogue: apply 1/l, store fp32 ----
  float* op = outg + base + (size_t)(w * 128 + rowb) * E;
#pragma unroll
  for (int r = 0; r < 4; ++r) {
#pragma unroll
    for (int nt = 0; nt < 4; ++nt) {
      op[(size_t)r * E + nt * 16 + li] = O[nt][r] * linv[r];
    }
  }
}

extern "C" void kernel_launch(void* const* d_in, const int* in_sizes, int n_in,
                              void* d_out, int out_size, void* d_ws, size_t ws_size,
                              hipStream_t stream) {
  const float* q  = (const float*)d_in[0];
  const float* k  = (const float*)d_in[1];
  const float* qr = (const float*)d_in[2];
  const float* kr = (const float*)d_in[3];
  const float* v  = (const float*)d_in[4];
  float* out = (float*)d_out;
  dim3 grid(NWIN, NBH);
  la_kernel<<<grid, dim3(512), SMEM_BYTES, stream>>>(q, k, qr, kr, v, out);
}